// Round 8
// baseline (418.273 us; speedup 1.0000x reference)
//
#include <hip/hip_runtime.h>
#include <hip/hip_cooperative_groups.h>
#include <stdint.h>

namespace cg = cooperative_groups;

#define VEC_DIM   128
#define N_WORDS   100000
#define CTX       8
#define N_SAMPLES 6
#define BATCH     16384
#define N_GROUPS  6250                 // N_WORDS / 16, exact
#define TOTAL_S   (BATCH * N_SAMPLES)  // 98304
#define CAP       64                   // slots/group; Poisson(15.7) P(>=64) ~ 1e-18
#define GRID      1536                 // 6 blocks/CU x 256 CUs -> co-resident guaranteed

// ---- workspace layout (bytes) ----
static constexpr size_t OFF_INPUTS  = 0;                      // 16384*128*4 = 8,388,608
static constexpr size_t OFF_COUNT   = 8388608;                // 6250 u32
static constexpr size_t OFF_RECORDS = OFF_COUNT + 25024;      // 6250*64 u32 = 1.6 MB

#define TILE_WRITE(buf, idx, v) do {                                   \
    int d_ = (idx) >> 2, c4_ = (idx) & 3;                              \
    tileT[buf][c4_ * 4 + 0][d_] = (v).x;                               \
    tileT[buf][c4_ * 4 + 1][d_] = (v).y;                               \
    tileT[buf][c4_ * 4 + 2][d_] = (v).z;                               \
    tileT[buf][c4_ * 4 + 3][d_] = (v).w;                               \
} while (0)

// ============ cooperative monolith ============
__global__ __launch_bounds__(256, 6) void k_all(
    const int* __restrict__ doc_ids, const int* __restrict__ context_ids,
    const int* __restrict__ sample_ids,
    const float* __restrict__ para, const float* __restrict__ words,
    const float* __restrict__ outs,
    float* __restrict__ inputs, uint32_t* __restrict__ count,
    uint32_t* __restrict__ records, float* __restrict__ logits)
{
    cg::grid_group gg = cg::this_grid();
    __shared__ float tileT[2][16][132];        // [buf][col][dim], padded rows (528 B)

    const int t   = threadIdx.x;
    const int bid = blockIdx.x;
    const int gid = bid * 256 + t;

    // ---- P0: zero per-group counters ----
    if (gid < N_GROUPS) count[gid] = 0u;
    gg.sync();

    // ---- P1a: bin all samples (one thread per record; 98304 < 393216) ----
    if (gid < TOTAL_S) {
        int id = sample_ids[gid];
        int g  = id >> 4;
        uint32_t pos = atomicAdd(&count[g], 1u);
        int bb = gid / N_SAMPLES;
        int ss = gid - bb * N_SAMPLES;
        if (pos < CAP)                         // memory-safety guard; never taken
            records[g * CAP + pos] =
                ((uint32_t)bb << 7) | ((uint32_t)ss << 4) | (uint32_t)(id & 15);
    }

    // ---- P1b: issue first tile's global loads (group g0 = bid), no wait ----
    float4 pf0, pf1;
    {
        int i0 = t,      d0 = i0 >> 2, c0 = i0 & 3;
        int i1 = t + 256, d1 = i1 >> 2, c1 = i1 & 3;
        pf0 = *reinterpret_cast<const float4*>(outs + (size_t)d0 * N_WORDS + bid * 16 + c0 * 4);
        pf1 = *reinterpret_cast<const float4*>(outs + (size_t)d1 * N_WORDS + bid * 16 + c1 * 4);
    }

    // ---- P1c: gather inputs (one wave per batch element, grid-stride) ----
    const int wave = t >> 6;
    const int lane = t & 63;
    for (int base = bid * 4; base < BATCH; base += GRID * 4) {
        const int b   = base + wave;
        const int doc = doc_ids[b];
        int cids[CTX];
        #pragma unroll
        for (int c = 0; c < CTX; ++c) cids[c] = context_ids[b * CTX + c];

        const float2* prow = reinterpret_cast<const float2*>(para + (size_t)doc * VEC_DIM);
        float2 acc = prow[lane];
        #pragma unroll
        for (int c = 0; c < CTX; ++c) {
            const float2* wrow = reinterpret_cast<const float2*>(words + (size_t)cids[c] * VEC_DIM);
            float2 w = wrow[lane];
            acc.x += w.x; acc.y += w.y;
        }
        reinterpret_cast<float2*>(inputs)[(size_t)b * 64 + lane] = acc;
    }

    // ---- P1d: commit prefetched tile to LDS buf 0 ----
    TILE_WRITE(0, t, pf0);
    TILE_WRITE(0, t + 256, pf1);

    gg.sync();                                 // records+inputs complete; buf0 visible

    // ---- P2: process groups grid-stride, double-buffered tiles ----
    const int slot = t >> 4;                   // 16 record-slots per block
    const int j    = t & 15;                   // lane-in-group: owns dims 8j..8j+7
    int cur = 0;
    for (int g = bid; g < N_GROUPS; g += GRID) {
        const int gn = g + GRID;
        float4 n0, n1;
        if (gn < N_GROUPS) {                   // issue next tile loads (no wait)
            int i0 = t,      d0 = i0 >> 2, c0 = i0 & 3;
            int i1 = t + 256, d1 = i1 >> 2, c1 = i1 & 3;
            n0 = *reinterpret_cast<const float4*>(outs + (size_t)d0 * N_WORDS + gn * 16 + c0 * 4);
            n1 = *reinterpret_cast<const float4*>(outs + (size_t)d1 * N_WORDS + gn * 16 + c1 * 4);
        }

        uint32_t n = count[g];
        if (n > CAP) n = CAP;                  // never taken
        for (uint32_t i = slot; i < n; i += 16) {
            uint32_t rec = records[g * CAP + i];
            int c = rec & 15;
            int s = (rec >> 4) & 7;
            int b = (int)(rec >> 7);

            const float4* inp4 = reinterpret_cast<const float4*>(inputs + (size_t)b * VEC_DIM);
            float4 a0 = inp4[j * 2];
            float4 a1 = inp4[j * 2 + 1];
            float4 w0 = *reinterpret_cast<const float4*>(&tileT[cur][c][j * 8]);
            float4 w1 = *reinterpret_cast<const float4*>(&tileT[cur][c][j * 8 + 4]);

            float p = a0.x * w0.x + a0.y * w0.y + a0.z * w0.z + a0.w * w0.w
                    + a1.x * w1.x + a1.y * w1.y + a1.z * w1.z + a1.w * w1.w;

            #pragma unroll
            for (int off = 1; off < 16; off <<= 1)
                p += __shfl_xor(p, off, 64);

            if (j == 0)
                logits[(size_t)b * N_SAMPLES + s] = p;
        }

        if (gn < N_GROUPS) {                   // commit next tile to other buffer
            TILE_WRITE(cur ^ 1, t, n0);
            TILE_WRITE(cur ^ 1, t + 256, n1);
        }
        __syncthreads();                       // buf swap barrier
        cur ^= 1;
    }
}

// ============ fallback path (proven R4 pipeline) ============
__global__ void k_zero(uint32_t* __restrict__ count) {
    int i = blockIdx.x * 256 + threadIdx.x;
    if (i < N_GROUPS) count[i] = 0u;
}

__global__ __launch_bounds__(256) void k_gather_append(
    const int* __restrict__ doc_ids, const int* __restrict__ context_ids,
    const int* __restrict__ sample_ids,
    const float* __restrict__ para, const float* __restrict__ words,
    float* __restrict__ inputs, uint32_t* __restrict__ count,
    uint32_t* __restrict__ records)
{
    const int t    = threadIdx.x;
    const int wave = t >> 6;
    const int lane = t & 63;
    const int b    = blockIdx.x * 4 + wave;

    if (t < 24) {
        int i  = blockIdx.x * 24 + t;
        int id = sample_ids[i];
        int g  = id >> 4;
        uint32_t pos = atomicAdd(&count[g], 1u);
        int bb = i / N_SAMPLES;
        int ss = i - bb * N_SAMPLES;
        if (pos < CAP)
            records[g * CAP + pos] =
                ((uint32_t)bb << 7) | ((uint32_t)ss << 4) | (uint32_t)(id & 15);
    }

    const int doc = doc_ids[b];
    int cids[CTX];
    #pragma unroll
    for (int c = 0; c < CTX; ++c) cids[c] = context_ids[b * CTX + c];

    const float2* prow = reinterpret_cast<const float2*>(para + (size_t)doc * VEC_DIM);
    float2 acc = prow[lane];
    #pragma unroll
    for (int c = 0; c < CTX; ++c) {
        const float2* wrow = reinterpret_cast<const float2*>(words + (size_t)cids[c] * VEC_DIM);
        float2 w = wrow[lane];
        acc.x += w.x; acc.y += w.y;
    }
    reinterpret_cast<float2*>(inputs)[(size_t)b * 64 + lane] = acc;
}

__global__ __launch_bounds__(256) void k_process(
    const float* __restrict__ outs,
    const float* __restrict__ inputs,
    const uint32_t* __restrict__ count,
    const uint32_t* __restrict__ records,
    float* __restrict__ logits)
{
    const int g = blockIdx.x;
    uint32_t n = count[g];
    if (n > CAP) n = CAP;
    if (n == 0) return;

    __shared__ float tileT[16][132];
    const int t = threadIdx.x;
    #pragma unroll
    for (int k = 0; k < 2; ++k) {
        int idx = t + k * 256;
        int d   = idx >> 2;
        int c4  = idx & 3;
        float4 v = *reinterpret_cast<const float4*>(
            outs + (size_t)d * N_WORDS + g * 16 + c4 * 4);
        tileT[c4 * 4 + 0][d] = v.x;
        tileT[c4 * 4 + 1][d] = v.y;
        tileT[c4 * 4 + 2][d] = v.z;
        tileT[c4 * 4 + 3][d] = v.w;
    }
    __syncthreads();

    const int slot = t >> 4;
    const int j    = t & 15;
    for (uint32_t i = slot; i < n; i += 16) {
        uint32_t rec = records[g * CAP + i];
        int c = rec & 15;
        int s = (rec >> 4) & 7;
        int b = (int)(rec >> 7);

        const float4* inp4 = reinterpret_cast<const float4*>(inputs + (size_t)b * VEC_DIM);
        float4 a0 = inp4[j * 2];
        float4 a1 = inp4[j * 2 + 1];
        float4 w0 = *reinterpret_cast<const float4*>(&tileT[c][j * 8]);
        float4 w1 = *reinterpret_cast<const float4*>(&tileT[c][j * 8 + 4]);

        float p = a0.x * w0.x + a0.y * w0.y + a0.z * w0.z + a0.w * w0.w
                + a1.x * w1.x + a1.y * w1.y + a1.z * w1.z + a1.w * w1.w;

        #pragma unroll
        for (int off = 1; off < 16; off <<= 1)
            p += __shfl_xor(p, off, 64);

        if (j == 0)
            logits[(size_t)b * N_SAMPLES + s] = p;
    }
}

extern "C" void kernel_launch(void* const* d_in, const int* in_sizes, int n_in,
                              void* d_out, int out_size, void* d_ws, size_t ws_size,
                              hipStream_t stream) {
    const int*   doc_ids     = (const int*)  d_in[0];
    const int*   context_ids = (const int*)  d_in[1];
    const int*   sample_ids  = (const int*)  d_in[2];
    const float* para        = (const float*)d_in[3];
    const float* words       = (const float*)d_in[4];
    const float* outs        = (const float*)d_in[5];
    float*       logits      = (float*)      d_out;

    char* ws = (char*)d_ws;
    float*    inputs  = (float*)   (ws + OFF_INPUTS);
    uint32_t* count   = (uint32_t*)(ws + OFF_COUNT);
    uint32_t* records = (uint32_t*)(ws + OFF_RECORDS);

    void* args[] = { (void*)&doc_ids, (void*)&context_ids, (void*)&sample_ids,
                     (void*)&para, (void*)&words, (void*)&outs,
                     (void*)&inputs, (void*)&count, (void*)&records, (void*)&logits };

    hipError_t err = hipLaunchCooperativeKernel((const void*)k_all, dim3(GRID), dim3(256),
                                                args, 0, stream);
    if (err != hipSuccess) {
        // cooperative launch unavailable (or not capturable) -> proven 3-kernel path
        (void)hipGetLastError();
        hipLaunchKernelGGL(k_zero, dim3((N_GROUPS + 255) / 256), dim3(256), 0, stream, count);
        hipLaunchKernelGGL(k_gather_append, dim3(BATCH / 4), dim3(256), 0, stream,
                           doc_ids, context_ids, sample_ids, para, words,
                           inputs, count, records);
        hipLaunchKernelGGL(k_process, dim3(N_GROUPS), dim3(256), 0, stream,
                           outs, inputs, count, records, logits);
    }
}

// Round 14
// 179.283 us; speedup vs baseline: 2.3330x; 2.3330x over previous
//
#include <hip/hip_runtime.h>
#include <stdint.h>

#define VEC_DIM   128
#define N_WORDS   100000
#define CTX       8
#define N_SAMPLES 6
#define BATCH     16384
#define N_GROUPS  6250                 // N_WORDS / 16, exact
#define TOTAL_S   (BATCH * N_SAMPLES)  // 98304
#define CAP       64                   // slots/group; Poisson(15.7) P(>=64) ~ 1e-18

typedef float f32x4 __attribute__((ext_vector_type(4)));  // native vec for nontemporal

// ---- workspace layout (bytes) ----
static constexpr size_t OFF_INPUTS  = 0;                      // 16384*128*4 = 8,388,608
static constexpr size_t OFF_COUNT   = 8388608;                // 6250 u32
static constexpr size_t OFF_RECORDS = OFF_COUNT + 25024;      // 6250*64 u32 = 1.6 MB

// K1: gather inputs (one wave per batch element) + fused record append.
//     4096 blocks x 256 threads; threads 0..23 also bin this block's 24 samples.
__global__ __launch_bounds__(256) void k_gather_append(
    const int* __restrict__ doc_ids, const int* __restrict__ context_ids,
    const int* __restrict__ sample_ids,
    const float* __restrict__ para, const float* __restrict__ words,
    float* __restrict__ inputs, uint32_t* __restrict__ count,
    uint32_t* __restrict__ records)
{
    const int t    = threadIdx.x;
    const int wave = t >> 6;
    const int lane = t & 63;
    const int b    = blockIdx.x * 4 + wave;

    // fused binning: 24 sample ids per block (4096 * 24 = 98304 exact)
    if (t < 24) {
        int i  = blockIdx.x * 24 + t;          // i = bb*N_SAMPLES + ss
        int id = sample_ids[i];
        int g  = id >> 4;
        uint32_t pos = atomicAdd(&count[g], 1u);
        int bb = i / N_SAMPLES;
        int ss = i - bb * N_SAMPLES;
        if (pos < CAP)                         // memory-safety guard; never taken
            records[g * CAP + pos] =
                ((uint32_t)bb << 7) | ((uint32_t)ss << 4) | (uint32_t)(id & 15);
    }

    const int doc = doc_ids[b];
    int cids[CTX];
    #pragma unroll
    for (int c = 0; c < CTX; ++c) cids[c] = context_ids[b * CTX + c];

    const float2* prow = reinterpret_cast<const float2*>(para + (size_t)doc * VEC_DIM);
    float2 acc = prow[lane];
    #pragma unroll
    for (int c = 0; c < CTX; ++c) {
        const float2* wrow = reinterpret_cast<const float2*>(words + (size_t)cids[c] * VEC_DIM);
        float2 w = wrow[lane];
        acc.x += w.x; acc.y += w.y;
    }
    reinterpret_cast<float2*>(inputs)[(size_t)b * 64 + lane] = acc;
}

// K2: one block per line-group; transposed 16x128 tile in LDS (nontemporal
//     float4 loads of the single-use outs stream); 16-lane groups each
//     process one record: lane j owns dims 8j..8j+7.
__global__ __launch_bounds__(256) void k_process(
    const float* __restrict__ outs,
    const float* __restrict__ inputs,
    const uint32_t* __restrict__ count,
    const uint32_t* __restrict__ records,
    float* __restrict__ logits)
{
    const int g = blockIdx.x;
    uint32_t n = count[g];
    if (n > CAP) n = CAP;                      // never taken
    if (n == 0) return;                        // uniform, before any sync

    __shared__ float tileT[16][132];           // [col][dim]; 528 B rows (16B-aligned)

    const int t = threadIdx.x;
    const int base_col = g * 16;
    // 512 float4 segments (128 rows x 4 quads), 2 per thread; streamed (no reuse)
    #pragma unroll
    for (int k = 0; k < 2; ++k) {
        int idx = t + k * 256;                 // 0..511
        int d   = idx >> 2;                    // row 0..127
        int c4  = idx & 3;                     // col quad
        f32x4 v = __builtin_nontemporal_load(
            reinterpret_cast<const f32x4*>(outs + (size_t)d * N_WORDS + base_col + c4 * 4));
        tileT[c4 * 4 + 0][d] = v.x;
        tileT[c4 * 4 + 1][d] = v.y;
        tileT[c4 * 4 + 2][d] = v.z;
        tileT[c4 * 4 + 3][d] = v.w;
    }
    __syncthreads();

    const int slot = t >> 4;                   // 16 record-slots per block
    const int j    = t & 15;                   // lane-in-group: owns dims 8j..8j+7

    for (uint32_t i = slot; i < n; i += 16) {
        uint32_t rec = records[g * CAP + i];   // broadcast within 16-lane group
        int c = rec & 15;
        int s = (rec >> 4) & 7;
        int b = (int)(rec >> 7);

        const float4* inp4 = reinterpret_cast<const float4*>(inputs + (size_t)b * VEC_DIM);
        float4 a0 = inp4[j * 2];
        float4 a1 = inp4[j * 2 + 1];
        float4 w0 = *reinterpret_cast<const float4*>(&tileT[c][j * 8]);
        float4 w1 = *reinterpret_cast<const float4*>(&tileT[c][j * 8 + 4]);

        float p = a0.x * w0.x + a0.y * w0.y + a0.z * w0.z + a0.w * w0.w
                + a1.x * w1.x + a1.y * w1.y + a1.z * w1.z + a1.w * w1.w;

        // reduce across the 16-lane group (xor 1,2,4,8 stays within group)
        #pragma unroll
        for (int off = 1; off < 16; off <<= 1)
            p += __shfl_xor(p, off, 64);

        if (j == 0)
            logits[(size_t)b * N_SAMPLES + s] = p;
    }
}

extern "C" void kernel_launch(void* const* d_in, const int* in_sizes, int n_in,
                              void* d_out, int out_size, void* d_ws, size_t ws_size,
                              hipStream_t stream) {
    const int*   doc_ids     = (const int*)  d_in[0];
    const int*   context_ids = (const int*)  d_in[1];
    const int*   sample_ids  = (const int*)  d_in[2];
    const float* para        = (const float*)d_in[3];
    const float* words       = (const float*)d_in[4];
    const float* outs        = (const float*)d_in[5];
    float*       logits      = (float*)      d_out;

    char* ws = (char*)d_ws;
    float*    inputs  = (float*)   (ws + OFF_INPUTS);
    uint32_t* count   = (uint32_t*)(ws + OFF_COUNT);
    uint32_t* records = (uint32_t*)(ws + OFF_RECORDS);

    // memset node instead of a zero-kernel (capture-legal: harness resets use it)
    (void)hipMemsetAsync(count, 0, N_GROUPS * sizeof(uint32_t), stream);
    hipLaunchKernelGGL(k_gather_append, dim3(BATCH / 4), dim3(256), 0, stream,
                       doc_ids, context_ids, sample_ids, para, words,
                       inputs, count, records);
    hipLaunchKernelGGL(k_process, dim3(N_GROUPS), dim3(256), 0, stream,
                       outs, inputs, count, records, logits);
}